// Round 14
// baseline (488.621 us; speedup 1.0000x reference)
//
#include <hip/hip_runtime.h>
#include <cstdint>
#include <cstddef>

#define NP     160000   // total points (B*T)
#define NB     8        // batch
#define TPB    20000    // points per batch
#define H      128      // hidden dim
#define SS     4096     // bins per plane (64*64)
#define NCHUNK 625      // TPB/32 (pool chunks)
#define NBLK   10       // sort chunks per (plane,batch)
#define PPB    2000     // points per sort chunk
#define NTILE  2500     // NP/64 point tiles

typedef _Float16 half8  __attribute__((ext_vector_type(8)));
typedef _Float16 half4v __attribute__((ext_vector_type(4)));
typedef float    f32x16 __attribute__((ext_vector_type(16)));

__device__ __forceinline__ half8 reluh8(half8 x) {
  half8 z = (half8)(_Float16)0;
  return __builtin_elementwise_max(x, z);   // 4x v_pk_max_f16
}

// ---------------- per-chunk histograms + idx compute (fused) ----------------
__global__ __launch_bounds__(256) void k_hist(const float* __restrict__ p,
                                              int* __restrict__ idx,
                                              unsigned* __restrict__ hist) {
  __shared__ unsigned lh[SS];
  const int tid = threadIdx.x;
  const int plb = blockIdx.x % 24;
  const int blk = blockIdx.x / 24;
  const int pl = plb >> 3, b = plb & 7;
  for (int j = tid; j < SS; j += 256) lh[j] = 0;
  __syncthreads();
  const float DEN = (float)(1.0 + 0.1 + 1e-3);
  const float HI  = (float)(1.0 - 1e-3);
  const int nbase = b*TPB + blk*PPB;
  for (int j = tid; j < PPB; j += 256) {
    const int n = nbase + j;
    const float px = p[3*n], py = p[3*n+1], pz = p[3*n+2];
    float ca, cb;                       // plane column picks: (0,2) (0,1) (1,2)
    if (pl == 0)      { ca = px; cb = pz; }
    else if (pl == 1) { ca = px; cb = py; }
    else              { ca = py; cb = pz; }
    const float na = fminf(fmaxf(ca / DEN + 0.5f, 0.0f), HI);
    const float nb = fminf(fmaxf(cb / DEN + 0.5f, 0.0f), HI);
    const int bin = (int)(na * 64.0f) + 64 * (int)(nb * 64.0f);
    idx[pl*NP + n] = bin;
    atomicAdd(&lh[bin], 1u);
  }
  __syncthreads();
  unsigned* dst = hist + ((size_t)plb*NBLK + blk)*SS;
  for (int j = tid; j < SS; j += 256) dst[j] = lh[j];
}

// ---------------- scan: totals -> cnt, bin ENDS -> cursor, in-place block bases ----
__global__ __launch_bounds__(256) void k_scan2(unsigned* __restrict__ hist,
                                               unsigned* __restrict__ cnt,
                                               int* __restrict__ cursor) {
  __shared__ unsigned stot[SS];
  __shared__ unsigned ssum[256];
  __shared__ unsigned sbase[256];
  const int plb = blockIdx.x;
  const int tid = threadIdx.x;
  unsigned* hp = hist + (size_t)plb*NBLK*SS;
  for (int j = tid; j < SS; j += 256) {
    unsigned t = 0;
    #pragma unroll
    for (int blk = 0; blk < NBLK; ++blk) t += hp[blk*SS + j];
    stot[j] = t;
  }
  __syncthreads();
  unsigned local = 0;
  #pragma unroll
  for (int i = 0; i < 16; ++i) local += stot[tid*16 + i];
  ssum[tid] = local;
  __syncthreads();
  if (tid == 0) {
    unsigned run = 0;
    for (int i = 0; i < 256; ++i) { sbase[i] = run; run += ssum[i]; }
  }
  __syncthreads();
  unsigned run = sbase[tid];
  for (int i = 0; i < 16; ++i) {
    const int bin = tid*16 + i;
    const unsigned tot = stot[bin];
    cnt[plb*SS + bin] = tot;
    cursor[plb*SS + bin] = (int)(run + tot);       // END offset of bin
    unsigned acc = run;                            // in-place: counts -> bases
    #pragma unroll
    for (int blk = 0; blk < NBLK; ++blk) {
      const unsigned c = hp[blk*SS + bin];
      hp[blk*SS + bin] = acc;
      acc += c;
    }
    run += tot;
  }
}

// ---------------- reorder: local rank via LDS atomics, plain global stores ----
__global__ __launch_bounds__(256) void k_reorder2(const int* __restrict__ idx,
                                                  const unsigned* __restrict__ hist,
                                                  int* __restrict__ order) {
  __shared__ unsigned lrank[SS];
  const int tid = threadIdx.x;
  const int plb = blockIdx.x % 24;
  const int blk = blockIdx.x / 24;
  const int pl = plb >> 3, b = plb & 7;
  for (int j = tid; j < SS; j += 256) lrank[j] = 0;
  __syncthreads();
  const unsigned* bp = hist + ((size_t)plb*NBLK + blk)*SS;
  int* op = order + pl*NP + b*TPB;
  const int nbase = b*TPB + blk*PPB;
  for (int j = tid; j < PPB; j += 256) {
    const int n = nbase + j;
    const int bin = idx[pl*NP + n];
    const unsigned r = atomicAdd(&lrank[bin], 1u);
    op[bp[bin] + r] = (bin << 18) | n;
  }
}

// ---------------- weights fp32 -> f16 in MFMA B-fragment order ----------------
__global__ __launch_bounds__(256) void k_wconv(const float* __restrict__ w0,
                                               const float* __restrict__ w1,
                                               const float* __restrict__ wsc,
                                               _Float16* __restrict__ wb) {
  int t = blockIdx.x*256 + threadIdx.x;
  if (t >= 51200) return;
  int L = t / 10240, r = t % 10240;
  const float* src; _Float16* dst; int q;
  if (r < 4096)      { q = r;        src = w0  + L*32768; dst = wb + L*81920;         }
  else if (r < 8192) { q = r - 4096; src = wsc + L*32768; dst = wb + L*81920 + 32768; }
  else               { q = r - 8192; src = w1  + L*16384; dst = wb + L*81920 + 65536; }
  int kt = q >> 8, nt = (q >> 6) & 3, l = q & 63;
  int k0 = kt*16 + ((l >> 5) << 3);
  int n  = nt*32 + (l & 31);
  union { _Float16 h[8]; uint4 u; } o;
  #pragma unroll
  for (int j = 0; j < 8; ++j) o.h[j] = (_Float16)src[(size_t)(k0 + j)*H + n];
  *(uint4*)(dst + (size_t)q*8) = o.u;
}

// ---------------- Phase A: chunked segmented reduce, single-writer, NO atomics ----
template<int OP>
__global__ __launch_bounds__(256) void k_poolA(const _Float16* __restrict__ net,
                                               const int* __restrict__ order,
                                               _Float16* __restrict__ fea,
                                               float* __restrict__ sums,
                                               float* __restrict__ pbufF,
                                               float* __restrict__ pbufL) {
  const int tid   = threadIdx.x;
  const int plb   = blockIdx.x % 24;
  const int chunk = (blockIdx.x / 24) * 8 + (tid >> 5);
  if (chunk >= NCHUNK) return;
  const int gi = tid & 31, f4 = gi << 2;
  const int pl = plb >> 3, b = plb & 7;
  const int base = pl*NP + b*TPB + chunk*32;
  const int pkv = order[base + gi];
  const int prevbin = (chunk > 0)          ? (order[base - 1] >> 18) : -1;
  const int nextbin = (chunk < NCHUNK - 1) ? (order[base + 32] >> 18) : -1;

  uint2 v[32];
  #pragma unroll
  for (int i = 0; i < 32; ++i) {
    const int pk = __shfl(pkv, i, 32);
    v[i] = *(const uint2*)&net[(size_t)(pk & 0x3FFFF)*H + f4];
  }
  __builtin_amdgcn_sched_barrier(0);

  const size_t pslot = ((size_t)plb*NCHUNK + chunk)*H + f4;
  int cur = __shfl(pkv, 0, 32) >> 18;
  int segstart = 0;
  float a0, a1, a2, a3;
  if (OP == 0) { a0 = a1 = a2 = a3 = -3.0e38f; } else { a0 = a1 = a2 = a3 = 0.f; }

  #pragma unroll
  for (int i = 0; i < 32; ++i) {
    const int bin = __shfl(pkv, i, 32) >> 18;
    if (bin != cur) {
      const bool contin = (segstart == 0) && (prevbin == cur);
      if (!contin) {
        if (OP == 0) {
          union { _Float16 h[4]; uint2 u; } o;
          o.h[0]=(_Float16)a0; o.h[1]=(_Float16)a1; o.h[2]=(_Float16)a2; o.h[3]=(_Float16)a3;
          *(uint2*)&fea[((size_t)plb*SS + cur)*H + f4] = o.u;
        } else {
          *(float4*)&sums[((size_t)plb*SS + cur)*H + f4] = make_float4(a0,a1,a2,a3);
        }
      } else {
        *(float4*)&pbufF[pslot] = make_float4(a0,a1,a2,a3);
      }
      cur = bin; segstart = i;
      if (OP == 0) { a0 = a1 = a2 = a3 = -3.0e38f; } else { a0 = a1 = a2 = a3 = 0.f; }
    }
    union { uint2 u; _Float16 h[4]; } w;
    w.u = v[i];
    if (OP == 0) {
      a0 = fmaxf(a0, (float)w.h[0]); a1 = fmaxf(a1, (float)w.h[1]);
      a2 = fmaxf(a2, (float)w.h[2]); a3 = fmaxf(a3, (float)w.h[3]);
    } else {
      a0 += (float)w.h[0]; a1 += (float)w.h[1];
      a2 += (float)w.h[2]; a3 += (float)w.h[3];
    }
  }
  const bool contin = (segstart == 0) && (prevbin == cur);
  const bool extend = (nextbin == cur);
  if (!contin && !extend) {
    if (OP == 0) {
      union { _Float16 h[4]; uint2 u; } o;
      o.h[0]=(_Float16)a0; o.h[1]=(_Float16)a1; o.h[2]=(_Float16)a2; o.h[3]=(_Float16)a3;
      *(uint2*)&fea[((size_t)plb*SS + cur)*H + f4] = o.u;
    } else {
      *(float4*)&sums[((size_t)plb*SS + cur)*H + f4] = make_float4(a0,a1,a2,a3);
    }
  } else if (contin) {
    *(float4*)&pbufF[pslot] = make_float4(a0,a1,a2,a3);
  } else {
    *(float4*)&pbufL[pslot] = make_float4(a0,a1,a2,a3);
  }
}

// ---------------- Phase B: combine cross-boundary bins (first boundary owns) ----
template<int OP>
__global__ __launch_bounds__(256) void k_poolB(const int* __restrict__ order,
                                               const int* __restrict__ cursor,
                                               _Float16* __restrict__ fea,
                                               float* __restrict__ sums,
                                               const float* __restrict__ pbufF,
                                               const float* __restrict__ pbufL) {
  const int tid = threadIdx.x;
  const int plb = blockIdx.x % 24;
  const int bnd = (blockIdx.x / 24) * 8 + (tid >> 5);
  if (bnd >= NCHUNK - 1) return;
  const int gi = tid & 31, f4 = gi << 2;
  const int pl = plb >> 3, b = plb & 7;
  const int base = pl*NP + b*TPB;
  const int pos  = (bnd + 1) * 32;
  const int binR = order[base + pos] >> 18;
  const int binL = order[base + pos - 1] >> 18;
  if (binL != binR) return;
  const int beta = binR;
  const int e = cursor[plb*SS + beta];
  const int s = (beta > 0) ? cursor[plb*SS + beta - 1] : 0;
  const int cs = s >> 5, ce = (e - 1) >> 5;
  if (cs != bnd) return;
  float4 acc = *(const float4*)&pbufL[((size_t)plb*NCHUNK + cs)*H + f4];
  #pragma unroll 4
  for (int c = cs + 1; c <= ce; ++c) {
    const float4 q = *(const float4*)&pbufF[((size_t)plb*NCHUNK + c)*H + f4];
    if (OP == 0) {
      acc.x = fmaxf(acc.x, q.x); acc.y = fmaxf(acc.y, q.y);
      acc.z = fmaxf(acc.z, q.z); acc.w = fmaxf(acc.w, q.w);
    } else {
      acc.x += q.x; acc.y += q.y; acc.z += q.z; acc.w += q.w;
    }
  }
  if (OP == 0) {
    union { _Float16 h[4]; uint2 u; } o;
    o.h[0]=(_Float16)acc.x; o.h[1]=(_Float16)acc.y;
    o.h[2]=(_Float16)acc.z; o.h[3]=(_Float16)acc.w;
    *(uint2*)&fea[((size_t)plb*SS + beta)*H + f4] = o.u;
  } else {
    *(float4*)&sums[((size_t)plb*SS + beta)*H + f4] = acc;
  }
}

// ---------------- fused ResnetBlockFC via mfma_f32_32x32x16_f16 ----------------
// R9 shape (best measured: 63.7us): 64-pt tile, 256 thr / 4 waves; wave w =
// col tile, covers ALL 64 rows x 32 cols -> 80 MFMA per 40KB weight fragments
// (max weight amortization; R13's 8-wave split doubled weight traffic).
// 64 acc regs + unroll 4/2 = 112 VGPR total, proven spill-free at (256,4).
// NEW vs R9: (a) XCD-pinned tile remap t=(bid&7)*314+(bid>>3) — same-batch
// tiles share an XCD so MODE1's fea gathers L2-hit (~3-6MB/XCD vs 24MB);
// (b) s_setprio(1) around MFMA clusters (blocks at different phases on a CU
// give the scheduler role diversity — T5 regime).
template<int MODE>
__global__ __launch_bounds__(256, 4) void k_block(
    const float* __restrict__ p,
    const float* __restrict__ wpos, const float* __restrict__ bpos,
    _Float16* __restrict__ net,
    const _Float16* __restrict__ fea, const int* __restrict__ idx,
    const _Float16* __restrict__ wb,
    const float* __restrict__ b0, const float* __restrict__ b1)
{
  __shared__ char smem[32768];
  char* Xs = smem;
  char* Hs = smem;            // alias — Xs dead after phase A
  const int t = (blockIdx.x & 7) * 314 + (blockIdx.x >> 3);   // XCD-pinned remap
  if (t >= NTILE) return;
  const int tid = threadIdx.x;
  const int n0  = t * 64;

  if (MODE == 0) {
    for (int j = tid; j < 64*64; j += 256) {
      int pt = j >> 6, k4 = (j & 63) << 2;
      int n = n0 + pt;
      float px = p[3*n], py = p[3*n+1], pz = p[3*n+2];
      float4 a  = *(const float4*)&bpos[k4];
      float4 wx = *(const float4*)&wpos[k4];
      float4 wy = *(const float4*)&wpos[256 + k4];
      float4 wz = *(const float4*)&wpos[512 + k4];
      a.x += px*wx.x + py*wy.x + pz*wz.x;
      a.y += px*wx.y + py*wy.y + pz*wz.y;
      a.z += px*wx.z + py*wy.z + pz*wz.z;
      a.w += px*wx.w + py*wy.w + pz*wz.w;
      union { _Float16 h[4]; uint2 u; } o;
      o.h[0] = (_Float16)a.x; o.h[1] = (_Float16)a.y;
      o.h[2] = (_Float16)a.z; o.h[3] = (_Float16)a.w;
      *(uint2*)(Xs + ((pt*512 + k4*2) ^ ((pt & 31) << 4))) = o.u;
    }
  } else {
    // merged staging: net-row copy + 3-plane gather; sums in packed f16
    for (int j = tid; j < 64*32; j += 256) {
      int pt = j >> 5, k4 = (j & 31) << 2;
      int n = n0 + pt;
      int b = n / TPB;
      uint2 vleft = *(const uint2*)&net[(size_t)n*H + k4];
      union { uint2 u; half4v h; } w0g, w1g, w2g, o;
      w0g.u = *(const uint2*)&fea[(((size_t)(0*NB + b))*SS + idx[0*NP + n])*H + k4];
      w1g.u = *(const uint2*)&fea[(((size_t)(1*NB + b))*SS + idx[1*NP + n])*H + k4];
      w2g.u = *(const uint2*)&fea[(((size_t)(2*NB + b))*SS + idx[2*NP + n])*H + k4];
      o.h = (w0g.h + w1g.h) + w2g.h;           // v_pk_add_f16
      const int sw = (pt & 31) << 4;
      *(uint2*)(Xs + ((pt*512 + k4*2) ^ sw)) = vleft;
      *(uint2*)(Xs + ((pt*512 + 256 + k4*2) ^ sw)) = o.u;
    }
  }
  __syncthreads();

  const int w  = tid >> 6;
  const int ln = tid & 63;
  const int l5 = ln >> 5;
  const int lr = ln & 31;
  const int sw = lr << 4;          // (row&31)<<4, same for rows lr and lr+32
  const int a0b = lr*512 + l5*16;
  const int a1b = a0b + 32*512;

  f32x16 aR0 = {}, aR1 = {}, aS0 = {}, aS1 = {};
  const _Float16* wb0 = wb;
  const _Float16* wbs = wb + 32768;

  __builtin_amdgcn_s_setprio(1);
  #pragma unroll 4
  for (int kt = 0; kt < 16; ++kt) {
    half8 x0 = *(const half8*)(Xs + ((a0b + kt*32) ^ sw));
    half8 x1 = *(const half8*)(Xs + ((a1b + kt*32) ^ sw));
    half8 r0 = reluh8(x0);
    half8 r1 = reluh8(x1);
    half8 bw = *(const half8*)(wb0 + ((kt*4 + w)*64 + ln)*8);
    half8 bs = *(const half8*)(wbs + ((kt*4 + w)*64 + ln)*8);
    aR0 = __builtin_amdgcn_mfma_f32_32x32x16_f16(r0, bw, aR0, 0, 0, 0);
    aR1 = __builtin_amdgcn_mfma_f32_32x32x16_f16(r1, bw, aR1, 0, 0, 0);
    aS0 = __builtin_amdgcn_mfma_f32_32x32x16_f16(x0, bs, aS0, 0, 0, 0);
    aS1 = __builtin_amdgcn_mfma_f32_32x32x16_f16(x1, bs, aS1, 0, 0, 0);
  }
  __builtin_amdgcn_s_setprio(0);
  __syncthreads();   // all waves done reading Xs before Hs aliases it

  // h = relu(fc0 + b0) -> Hs  (C/D: col = lane&31, row = (reg&3)+8*(reg>>2)+4*(lane>>5))
  const int col = w*32 + lr;
  const float bb0 = b0[col];
  #pragma unroll
  for (int reg = 0; reg < 16; ++reg) {
    int ro = (reg & 3) + 8*(reg >> 2) + 4*l5;
    float v0 = fmaxf(aR0[reg] + bb0, 0.f);
    float v1 = fmaxf(aR1[reg] + bb0, 0.f);
    *(_Float16*)(Hs + ((ro*256 + col*2) ^ ((ro & 15) << 4)))      = (_Float16)v0;
    *(_Float16*)(Hs + (((32+ro)*256 + col*2) ^ ((ro & 15) << 4))) = (_Float16)v1;
  }
  __syncthreads();

  const _Float16* wb1 = wb + 65536;
  const int sw1 = (lr & 15) << 4;  // same for rows lr and lr+32
  __builtin_amdgcn_s_setprio(1);
  #pragma unroll 2
  for (int kt = 0; kt < 8; ++kt) {
    half8 h0 = *(const half8*)(Hs + ((lr*256 + l5*16 + kt*32) ^ sw1));
    half8 h1 = *(const half8*)(Hs + (((32+lr)*256 + l5*16 + kt*32) ^ sw1));
    half8 bf = *(const half8*)(wb1 + ((kt*4 + w)*64 + ln)*8);
    aS0 = __builtin_amdgcn_mfma_f32_32x32x16_f16(h0, bf, aS0, 0, 0, 0);
    aS1 = __builtin_amdgcn_mfma_f32_32x32x16_f16(h1, bf, aS1, 0, 0, 0);
  }
  __builtin_amdgcn_s_setprio(0);

  const float bb1 = b1[col];
  #pragma unroll
  for (int reg = 0; reg < 16; ++reg) {
    int ro = (reg & 3) + 8*(reg >> 2) + 4*l5;
    net[(size_t)(n0 + ro)*H + col]      = (_Float16)(aS0[reg] + bb1);
    net[(size_t)(n0 + 32 + ro)*H + col] = (_Float16)(aS1[reg] + bb1);
  }
}

// ---------------- mean-normalize + fc_c GEMM + transpose-out ----------------
__global__ __launch_bounds__(256) void k_out2(const float* __restrict__ sums,
                                              const unsigned* __restrict__ cnt,
                                              const float* __restrict__ wc,
                                              const float* __restrict__ bc,
                                              float* __restrict__ out) {
  __shared__ float xa[64][132];
  const int plb = blockIdx.y;
  const int s0  = blockIdx.x << 6;
  const int tid = threadIdx.x;

  for (int j = tid; j < 64*32; j += 256) {
    int si = j >> 5, k4 = (j & 31) << 2;
    int s = s0 + si;
    float4 v = *(const float4*)&sums[((size_t)plb*SS + s)*H + k4];
    unsigned c = cnt[(size_t)plb*SS + s];
    float m = (c > 0u) ? (1.0f / (float)c) : 0.0f;   // empty bin -> 0
    xa[si][k4+0] = v.x*m; xa[si][k4+1] = v.y*m;
    xa[si][k4+2] = v.z*m; xa[si][k4+3] = v.w*m;
  }
  __syncthreads();

  const int fg = tid & 31;
  const int pg = tid >> 5;
  const int f4c = fg << 2;
  const int prow = pg << 3;
  float ac[8][4];
  #pragma unroll
  for (int i = 0; i < 8; ++i) { ac[i][0]=ac[i][1]=ac[i][2]=ac[i][3]=0.f; }
  #pragma unroll 4
  for (int k = 0; k < H; ++k) {
    const float4 wv = *(const float4*)&wc[(size_t)k*H + f4c];
    #pragma unroll
    for (int i = 0; i < 8; ++i) {
      const float xv = xa[prow + i][k];
      ac[i][0] += xv*wv.x; ac[i][1] += xv*wv.y; ac[i][2] += xv*wv.z; ac[i][3] += xv*wv.w;
    }
  }
  __syncthreads();
  const float4 bv = *(const float4*)&bc[f4c];
  #pragma unroll
  for (int i = 0; i < 8; ++i) {
    float4 o;
    o.x = ac[i][0] + bv.x;
    o.y = ac[i][1] + bv.y;
    o.z = ac[i][2] + bv.z;
    o.w = ac[i][3] + bv.w;
    *(float4*)&xa[prow + i][f4c] = o;
  }
  __syncthreads();

  for (int j = tid; j < H * 16; j += 256) {
    const int ch = j >> 4;
    const int s4 = (j & 15) << 2;
    float4 o;
    o.x = xa[s4 + 0][ch];
    o.y = xa[s4 + 1][ch];
    o.z = xa[s4 + 2][ch];
    o.w = xa[s4 + 3][ch];
    *(float4*)&out[((size_t)plb*H + ch)*SS + s0 + s4] = o;
  }
}

extern "C" void kernel_launch(void* const* d_in, const int* in_sizes, int n_in,
                              void* d_out, int out_size, void* d_ws, size_t ws_size,
                              hipStream_t stream) {
  (void)in_sizes; (void)n_in; (void)out_size; (void)ws_size;
  const float* p      = (const float*)d_in[0];
  const float* wpos   = (const float*)d_in[1];
  const float* bpos   = (const float*)d_in[2];
  const float* blk0w  = (const float*)d_in[3];
  const float* blk0b  = (const float*)d_in[4];
  const float* blk1w  = (const float*)d_in[5];
  const float* blk1b  = (const float*)d_in[6];
  const float* blkscw = (const float*)d_in[7];
  const float* wc     = (const float*)d_in[8];
  const float* bc     = (const float*)d_in[9];
  float* out = (float*)d_out;

  char* ws = (char*)d_ws;
  _Float16* net  = (_Float16*)ws;                    // NP*H*2        = 40,960,000
  int* idx       = (int*)(ws + 40960000);            // 3*NP*4        =  1,920,000
  int* order     = (int*)(ws + 42880000);            // 3*NP*4        =  1,920,000
  int* cursor    = (int*)(ws + 44800000);            // 24*SS*4       =    393,216
  unsigned* cnt  = (unsigned*)(ws + 45193216);       // 24*SS*4       =    393,216
  _Float16* wb   = (_Float16*)(ws + 45586432);       // 5*81920*2     =    819,200
  float* sums    = (float*)(ws + 46405632);          // 24*SS*H*4     = 50,331,648
  float* pbufF   = (float*)(ws + 96737280);          // 24*625*H*4    =  7,680,000
  float* pbufL   = (float*)(ws + 104417280);         // 24*625*H*4    =  7,680,000
  unsigned* hist = (unsigned*)(ws + 112097280);      // 24*10*SS*4    =  3,932,160
                                                     // total         116,029,440 B
  _Float16* fea  = (_Float16*)d_out;                 // 25,165,824 B, dead before k_out2

  k_hist<<<24*NBLK, 256, 0, stream>>>(p, idx, hist);
  k_scan2<<<24, 256, 0, stream>>>(hist, cnt, cursor);
  k_reorder2<<<24*NBLK, 256, 0, stream>>>(idx, hist, order);
  k_wconv<<<200, 256, 0, stream>>>(blk0w, blk1w, blkscw, wb);

  k_block<0><<<2512, 256, 0, stream>>>(p, wpos, bpos, net, nullptr, idx,
                                       wb, blk0b, blk1b);

  for (int i = 1; i < 5; ++i) {
    k_poolA<0><<<79*24, 256, 0, stream>>>(net, order, fea, nullptr, pbufF, pbufL);
    k_poolB<0><<<78*24, 256, 0, stream>>>(order, cursor, fea, nullptr, pbufF, pbufL);
    k_block<1><<<2512, 256, 0, stream>>>(nullptr, nullptr, nullptr, net, fea, idx,
                                         wb + (size_t)i*81920,
                                         blk0b + (size_t)i*H,
                                         blk1b + (size_t)i*H);
  }

  k_poolA<1><<<79*24, 256, 0, stream>>>(net, order, nullptr, sums, pbufF, pbufL);
  k_poolB<1><<<78*24, 256, 0, stream>>>(order, cursor, nullptr, sums, pbufF, pbufL);
  k_out2<<<dim3(64, 24), 256, 0, stream>>>(sums, cnt, wc, bc, out);
}

// Round 15
// 486.459 us; speedup vs baseline: 1.0044x; 1.0044x over previous
//
#include <hip/hip_runtime.h>
#include <cstdint>
#include <cstddef>

#define NP     160000   // total points (B*T)
#define NB     8        // batch
#define TPB    20000    // points per batch
#define H      128      // hidden dim
#define SS     4096     // bins per plane (64*64)
#define NCHUNK 625      // TPB/32 (pool chunks)
#define NBLK   10       // sort chunks per (plane,batch)
#define PPB    2000     // points per sort chunk
#define NTILE  2500     // NP/64 point tiles
#define GRID1  512      // persistent MODE1 grid (2 blocks/CU)

typedef _Float16 half8  __attribute__((ext_vector_type(8)));
typedef _Float16 half4v __attribute__((ext_vector_type(4)));
typedef float    f32x16 __attribute__((ext_vector_type(16)));

__device__ __forceinline__ half8 reluh8(half8 x) {
  half8 z = (half8)(_Float16)0;
  return __builtin_elementwise_max(x, z);   // 4x v_pk_max_f16
}

// ---------------- per-chunk histograms + idx compute (fused) ----------------
__global__ __launch_bounds__(256) void k_hist(const float* __restrict__ p,
                                              int* __restrict__ idx,
                                              unsigned* __restrict__ hist) {
  __shared__ unsigned lh[SS];
  const int tid = threadIdx.x;
  const int plb = blockIdx.x % 24;
  const int blk = blockIdx.x / 24;
  const int pl = plb >> 3, b = plb & 7;
  for (int j = tid; j < SS; j += 256) lh[j] = 0;
  __syncthreads();
  const float DEN = (float)(1.0 + 0.1 + 1e-3);
  const float HI  = (float)(1.0 - 1e-3);
  const int nbase = b*TPB + blk*PPB;
  for (int j = tid; j < PPB; j += 256) {
    const int n = nbase + j;
    const float px = p[3*n], py = p[3*n+1], pz = p[3*n+2];
    float ca, cb;                       // plane column picks: (0,2) (0,1) (1,2)
    if (pl == 0)      { ca = px; cb = pz; }
    else if (pl == 1) { ca = px; cb = py; }
    else              { ca = py; cb = pz; }
    const float na = fminf(fmaxf(ca / DEN + 0.5f, 0.0f), HI);
    const float nb = fminf(fmaxf(cb / DEN + 0.5f, 0.0f), HI);
    const int bin = (int)(na * 64.0f) + 64 * (int)(nb * 64.0f);
    idx[pl*NP + n] = bin;
    atomicAdd(&lh[bin], 1u);
  }
  __syncthreads();
  unsigned* dst = hist + ((size_t)plb*NBLK + blk)*SS;
  for (int j = tid; j < SS; j += 256) dst[j] = lh[j];
}

// ---------------- scan: totals -> cnt, bin ENDS -> cursor, in-place block bases ----
__global__ __launch_bounds__(256) void k_scan2(unsigned* __restrict__ hist,
                                               unsigned* __restrict__ cnt,
                                               int* __restrict__ cursor) {
  __shared__ unsigned stot[SS];
  __shared__ unsigned ssum[256];
  __shared__ unsigned sbase[256];
  const int plb = blockIdx.x;
  const int tid = threadIdx.x;
  unsigned* hp = hist + (size_t)plb*NBLK*SS;
  for (int j = tid; j < SS; j += 256) {
    unsigned t = 0;
    #pragma unroll
    for (int blk = 0; blk < NBLK; ++blk) t += hp[blk*SS + j];
    stot[j] = t;
  }
  __syncthreads();
  unsigned local = 0;
  #pragma unroll
  for (int i = 0; i < 16; ++i) local += stot[tid*16 + i];
  ssum[tid] = local;
  __syncthreads();
  if (tid == 0) {
    unsigned run = 0;
    for (int i = 0; i < 256; ++i) { sbase[i] = run; run += ssum[i]; }
  }
  __syncthreads();
  unsigned run = sbase[tid];
  for (int i = 0; i < 16; ++i) {
    const int bin = tid*16 + i;
    const unsigned tot = stot[bin];
    cnt[plb*SS + bin] = tot;
    cursor[plb*SS + bin] = (int)(run + tot);       // END offset of bin
    unsigned acc = run;                            // in-place: counts -> bases
    #pragma unroll
    for (int blk = 0; blk < NBLK; ++blk) {
      const unsigned c = hp[blk*SS + bin];
      hp[blk*SS + bin] = acc;
      acc += c;
    }
    run += tot;
  }
}

// ---------------- reorder: local rank via LDS atomics, plain global stores ----
__global__ __launch_bounds__(256) void k_reorder2(const int* __restrict__ idx,
                                                  const unsigned* __restrict__ hist,
                                                  int* __restrict__ order) {
  __shared__ unsigned lrank[SS];
  const int tid = threadIdx.x;
  const int plb = blockIdx.x % 24;
  const int blk = blockIdx.x / 24;
  const int pl = plb >> 3, b = plb & 7;
  for (int j = tid; j < SS; j += 256) lrank[j] = 0;
  __syncthreads();
  const unsigned* bp = hist + ((size_t)plb*NBLK + blk)*SS;
  int* op = order + pl*NP + b*TPB;
  const int nbase = b*TPB + blk*PPB;
  for (int j = tid; j < PPB; j += 256) {
    const int n = nbase + j;
    const int bin = idx[pl*NP + n];
    const unsigned r = atomicAdd(&lrank[bin], 1u);
    op[bp[bin] + r] = (bin << 18) | n;
  }
}

// ---------------- weights fp32 -> f16 in MFMA B-fragment order ----------------
__global__ __launch_bounds__(256) void k_wconv(const float* __restrict__ w0,
                                               const float* __restrict__ w1,
                                               const float* __restrict__ wsc,
                                               _Float16* __restrict__ wb) {
  int t = blockIdx.x*256 + threadIdx.x;
  if (t >= 51200) return;
  int L = t / 10240, r = t % 10240;
  const float* src; _Float16* dst; int q;
  if (r < 4096)      { q = r;        src = w0  + L*32768; dst = wb + L*81920;         }
  else if (r < 8192) { q = r - 4096; src = wsc + L*32768; dst = wb + L*81920 + 32768; }
  else               { q = r - 8192; src = w1  + L*16384; dst = wb + L*81920 + 65536; }
  int kt = q >> 8, nt = (q >> 6) & 3, l = q & 63;
  int k0 = kt*16 + ((l >> 5) << 3);
  int n  = nt*32 + (l & 31);
  union { _Float16 h[8]; uint4 u; } o;
  #pragma unroll
  for (int j = 0; j < 8; ++j) o.h[j] = (_Float16)src[(size_t)(k0 + j)*H + n];
  *(uint4*)(dst + (size_t)q*8) = o.u;
}

// ---------------- Phase A: chunked segmented reduce, single-writer, NO atomics ----
template<int OP>
__global__ __launch_bounds__(256) void k_poolA(const _Float16* __restrict__ net,
                                               const int* __restrict__ order,
                                               _Float16* __restrict__ fea,
                                               float* __restrict__ sums,
                                               float* __restrict__ pbufF,
                                               float* __restrict__ pbufL) {
  const int tid   = threadIdx.x;
  const int plb   = blockIdx.x % 24;
  const int chunk = (blockIdx.x / 24) * 8 + (tid >> 5);
  if (chunk >= NCHUNK) return;
  const int gi = tid & 31, f4 = gi << 2;
  const int pl = plb >> 3, b = plb & 7;
  const int base = pl*NP + b*TPB + chunk*32;
  const int pkv = order[base + gi];
  const int prevbin = (chunk > 0)          ? (order[base - 1] >> 18) : -1;
  const int nextbin = (chunk < NCHUNK - 1) ? (order[base + 32] >> 18) : -1;

  uint2 v[32];
  #pragma unroll
  for (int i = 0; i < 32; ++i) {
    const int pk = __shfl(pkv, i, 32);
    v[i] = *(const uint2*)&net[(size_t)(pk & 0x3FFFF)*H + f4];
  }
  __builtin_amdgcn_sched_barrier(0);

  const size_t pslot = ((size_t)plb*NCHUNK + chunk)*H + f4;
  int cur = __shfl(pkv, 0, 32) >> 18;
  int segstart = 0;
  float a0, a1, a2, a3;
  if (OP == 0) { a0 = a1 = a2 = a3 = -3.0e38f; } else { a0 = a1 = a2 = a3 = 0.f; }

  #pragma unroll
  for (int i = 0; i < 32; ++i) {
    const int bin = __shfl(pkv, i, 32) >> 18;
    if (bin != cur) {
      const bool contin = (segstart == 0) && (prevbin == cur);
      if (!contin) {
        if (OP == 0) {
          union { _Float16 h[4]; uint2 u; } o;
          o.h[0]=(_Float16)a0; o.h[1]=(_Float16)a1; o.h[2]=(_Float16)a2; o.h[3]=(_Float16)a3;
          *(uint2*)&fea[((size_t)plb*SS + cur)*H + f4] = o.u;
        } else {
          *(float4*)&sums[((size_t)plb*SS + cur)*H + f4] = make_float4(a0,a1,a2,a3);
        }
      } else {
        *(float4*)&pbufF[pslot] = make_float4(a0,a1,a2,a3);
      }
      cur = bin; segstart = i;
      if (OP == 0) { a0 = a1 = a2 = a3 = -3.0e38f; } else { a0 = a1 = a2 = a3 = 0.f; }
    }
    union { uint2 u; _Float16 h[4]; } w;
    w.u = v[i];
    if (OP == 0) {
      a0 = fmaxf(a0, (float)w.h[0]); a1 = fmaxf(a1, (float)w.h[1]);
      a2 = fmaxf(a2, (float)w.h[2]); a3 = fmaxf(a3, (float)w.h[3]);
    } else {
      a0 += (float)w.h[0]; a1 += (float)w.h[1];
      a2 += (float)w.h[2]; a3 += (float)w.h[3];
    }
  }
  const bool contin = (segstart == 0) && (prevbin == cur);
  const bool extend = (nextbin == cur);
  if (!contin && !extend) {
    if (OP == 0) {
      union { _Float16 h[4]; uint2 u; } o;
      o.h[0]=(_Float16)a0; o.h[1]=(_Float16)a1; o.h[2]=(_Float16)a2; o.h[3]=(_Float16)a3;
      *(uint2*)&fea[((size_t)plb*SS + cur)*H + f4] = o.u;
    } else {
      *(float4*)&sums[((size_t)plb*SS + cur)*H + f4] = make_float4(a0,a1,a2,a3);
    }
  } else if (contin) {
    *(float4*)&pbufF[pslot] = make_float4(a0,a1,a2,a3);
  } else {
    *(float4*)&pbufL[pslot] = make_float4(a0,a1,a2,a3);
  }
}

// ---------------- Phase B: combine cross-boundary bins (first boundary owns) ----
template<int OP>
__global__ __launch_bounds__(256) void k_poolB(const int* __restrict__ order,
                                               const int* __restrict__ cursor,
                                               _Float16* __restrict__ fea,
                                               float* __restrict__ sums,
                                               const float* __restrict__ pbufF,
                                               const float* __restrict__ pbufL) {
  const int tid = threadIdx.x;
  const int plb = blockIdx.x % 24;
  const int bnd = (blockIdx.x / 24) * 8 + (tid >> 5);
  if (bnd >= NCHUNK - 1) return;
  const int gi = tid & 31, f4 = gi << 2;
  const int pl = plb >> 3, b = plb & 7;
  const int base = pl*NP + b*TPB;
  const int pos  = (bnd + 1) * 32;
  const int binR = order[base + pos] >> 18;
  const int binL = order[base + pos - 1] >> 18;
  if (binL != binR) return;
  const int beta = binR;
  const int e = cursor[plb*SS + beta];
  const int s = (beta > 0) ? cursor[plb*SS + beta - 1] : 0;
  const int cs = s >> 5, ce = (e - 1) >> 5;
  if (cs != bnd) return;
  float4 acc = *(const float4*)&pbufL[((size_t)plb*NCHUNK + cs)*H + f4];
  #pragma unroll 4
  for (int c = cs + 1; c <= ce; ++c) {
    const float4 q = *(const float4*)&pbufF[((size_t)plb*NCHUNK + c)*H + f4];
    if (OP == 0) {
      acc.x = fmaxf(acc.x, q.x); acc.y = fmaxf(acc.y, q.y);
      acc.z = fmaxf(acc.z, q.z); acc.w = fmaxf(acc.w, q.w);
    } else {
      acc.x += q.x; acc.y += q.y; acc.z += q.z; acc.w += q.w;
    }
  }
  if (OP == 0) {
    union { _Float16 h[4]; uint2 u; } o;
    o.h[0]=(_Float16)acc.x; o.h[1]=(_Float16)acc.y;
    o.h[2]=(_Float16)acc.z; o.h[3]=(_Float16)acc.w;
    *(uint2*)&fea[((size_t)plb*SS + beta)*H + f4] = o.u;
  } else {
    *(float4*)&sums[((size_t)plb*SS + beta)*H + f4] = acc;
  }
}

// ---------------- fused ResnetBlockFC via mfma_f32_32x32x16_f16 ----------------
// R12 base (best measured 471us): 512 thr / 8 waves; wave w owns a 32x32
// output tile (c=w&3, r=w>>2); deferred shortcut keeps only 16 acc regs live.
// NEW (MODE1 only): PERSISTENT grid (512 = 2 blocks/CU) + T14 cross-tile
// register prefetch — pre[4][4] uint2 (32 regs, static idx) holds tile t's
// stage data; after stage-writing t to LDS, issue t+1's loads, then compute.
// The ~300-600cy gather latency hides under ~3us of MFMA. Barriers unchanged
// (B1->B2 barrier drains Xs readers; loop-top barrier drains Hs readers).
// (512,4): VGPR cap 128 >= ~45 arch + 32 pre + 16 acc. MODE0 = R12 verbatim.
template<int MODE>
__global__ __launch_bounds__(512, 4) void k_block(
    const float* __restrict__ p,
    const float* __restrict__ wpos, const float* __restrict__ bpos,
    _Float16* __restrict__ net,
    const _Float16* __restrict__ fea, const int* __restrict__ idx,
    const _Float16* __restrict__ wb,
    const float* __restrict__ b0, const float* __restrict__ b1)
{
  __shared__ char smem[49152];
  char* Xs = smem;            // x[64][256] f16, swz (row&31)<<4
  char* Hs = smem + 32768;    // h[64][128] f16, swz (row&15)<<4
  const int tid = threadIdx.x;

  const int w  = tid >> 6;          // wave 0..7
  const int c  = w & 3;             // col tile
  const int r  = w >> 2;            // row half
  const int ln = tid & 63;
  const int l5 = ln >> 5;
  const int lr = ln & 31;
  const int swx   = lr << 4;        // Xs swizzle; (r*32)&31 == 0
  const int xbase = lr*512 + l5*16 + r*16384;
  const int col   = c*32 + lr;
  const int hbase = (r*32 + lr)*256 + l5*16;
  const int swh   = (lr & 15) << 4;
  const float bb0 = b0[col];
  const float bb1 = b1[col];
  const _Float16* wb0 = wb;
  const _Float16* wbs = wb + 32768;
  const _Float16* wb1 = wb + 65536;

  auto COMPUTE = [&](int n0) {
    // ---- phase A: fc0 on relu(x), K=256 (16 acc regs) ----
    f32x16 aR = {};
    #pragma unroll 4
    for (int kt = 0; kt < 16; ++kt) {
      half8 x  = *(const half8*)(Xs + ((xbase + kt*32) ^ swx));
      half8 rx = reluh8(x);
      half8 bw = *(const half8*)(wb0 + ((kt*4 + c)*64 + ln)*8);
      aR = __builtin_amdgcn_mfma_f32_32x32x16_f16(rx, bw, aR, 0, 0, 0);
    }
    // h = relu(aR + b0) -> Hs (C/D: col=lane&31, row=(reg&3)+8*(reg>>2)+4*(lane>>5))
    #pragma unroll
    for (int reg = 0; reg < 16; ++reg) {
      const int ro  = (reg & 3) + 8*(reg >> 2) + 4*l5;
      const int row = r*32 + ro;
      const float v = fmaxf(aR[reg] + bb0, 0.f);
      *(_Float16*)(Hs + ((row*256 + col*2) ^ ((row & 15) << 4))) = (_Float16)v;
    }
    // ---- phase B1: shortcut x@Wsc (reads Xs only — overlaps the barrier) ----
    f32x16 aS = {};
    #pragma unroll 4
    for (int kt = 0; kt < 16; ++kt) {
      half8 x  = *(const half8*)(Xs + ((xbase + kt*32) ^ swx));
      half8 bs = *(const half8*)(wbs + ((kt*4 + c)*64 + ln)*8);
      aS = __builtin_amdgcn_mfma_f32_32x32x16_f16(x, bs, aS, 0, 0, 0);
    }
    __syncthreads();   // Hs writes from all waves visible; Xs readers drained
    // ---- phase B2: dx = h@W1, accumulate into aS ----
    #pragma unroll 2
    for (int kt = 0; kt < 8; ++kt) {
      half8 h  = *(const half8*)(Hs + ((hbase + kt*32) ^ swh));
      half8 bf = *(const half8*)(wb1 + ((kt*4 + c)*64 + ln)*8);
      aS = __builtin_amdgcn_mfma_f32_32x32x16_f16(h, bf, aS, 0, 0, 0);
    }
    #pragma unroll
    for (int reg = 0; reg < 16; ++reg) {
      const int ro = (reg & 3) + 8*(reg >> 2) + 4*l5;
      net[(size_t)(n0 + r*32 + ro)*H + col] = (_Float16)(aS[reg] + bb1);
    }
  };

  if (MODE == 0) {
    const int n0 = blockIdx.x * 64;
    for (int j = tid; j < 64*64; j += 512) {
      int pt = j >> 6, k4 = (j & 63) << 2;
      int n = n0 + pt;
      float px = p[3*n], py = p[3*n+1], pz = p[3*n+2];
      float4 a  = *(const float4*)&bpos[k4];
      float4 wx = *(const float4*)&wpos[k4];
      float4 wy = *(const float4*)&wpos[256 + k4];
      float4 wz = *(const float4*)&wpos[512 + k4];
      a.x += px*wx.x + py*wy.x + pz*wz.x;
      a.y += px*wx.y + py*wy.y + pz*wz.y;
      a.z += px*wx.z + py*wy.z + pz*wz.z;
      a.w += px*wx.w + py*wy.w + pz*wz.w;
      union { _Float16 h[4]; uint2 u; } o;
      o.h[0] = (_Float16)a.x; o.h[1] = (_Float16)a.y;
      o.h[2] = (_Float16)a.z; o.h[3] = (_Float16)a.w;
      *(uint2*)(Xs + ((pt*512 + k4*2) ^ ((pt & 31) << 4))) = o.u;
    }
    __syncthreads();
    COMPUTE(n0);
    return;
  }

  // ---- MODE 1: persistent + register prefetch (T14) ----
  const int pt0 = tid >> 5;              // 0..15
  const int k4  = (tid & 31) << 2;
  uint2 pre[4][4];                       // [iter][net, fea0, fea1, fea2] — static idx
  auto LOADT = [&](int tt) {
    #pragma unroll
    for (int i = 0; i < 4; ++i) {
      const int pt = pt0 + i*16;
      const int n  = tt*64 + pt;
      const int b  = n / TPB;
      pre[i][0] = *(const uint2*)&net[(size_t)n*H + k4];
      pre[i][1] = *(const uint2*)&fea[(((size_t)(0*NB + b))*SS + idx[0*NP + n])*H + k4];
      pre[i][2] = *(const uint2*)&fea[(((size_t)(1*NB + b))*SS + idx[1*NP + n])*H + k4];
      pre[i][3] = *(const uint2*)&fea[(((size_t)(2*NB + b))*SS + idx[2*NP + n])*H + k4];
    }
  };

  int t = blockIdx.x;
  LOADT(t);
  while (t < NTILE) {
    // stage-write tile t from regs (B1->B2 barrier of prev iter drained Xs readers)
    #pragma unroll
    for (int i = 0; i < 4; ++i) {
      const int pt = pt0 + i*16;
      union { uint2 u; half4v h; } g0, g1, g2, o;
      g0.u = pre[i][1]; g1.u = pre[i][2]; g2.u = pre[i][3];
      o.h = (g0.h + g1.h) + g2.h;        // v_pk_add_f16
      const int sw = (pt & 31) << 4;
      *(uint2*)(Xs + ((pt*512 + k4*2) ^ sw)) = pre[i][0];
      *(uint2*)(Xs + ((pt*512 + 256 + k4*2) ^ sw)) = o.u;
    }
    const int tn = t + (int)gridDim.x;
    if (tn < NTILE) LOADT(tn);           // issue next tile's loads NOW (hide under compute)
    __syncthreads();                     // stage visible; prev-iter Hs readers drained
    COMPUTE(t * 64);
    t = tn;
  }
}

// ---------------- mean-normalize + fc_c GEMM + transpose-out ----------------
__global__ __launch_bounds__(256) void k_out2(const float* __restrict__ sums,
                                              const unsigned* __restrict__ cnt,
                                              const float* __restrict__ wc,
                                              const float* __restrict__ bc,
                                              float* __restrict__ out) {
  __shared__ float xa[64][132];
  const int plb = blockIdx.y;
  const int s0  = blockIdx.x << 6;
  const int tid = threadIdx.x;

  for (int j = tid; j < 64*32; j += 256) {
    int si = j >> 5, k4 = (j & 31) << 2;
    int s = s0 + si;
    float4 v = *(const float4*)&sums[((size_t)plb*SS + s)*H + k4];
    unsigned c = cnt[(size_t)plb*SS + s];
    float m = (c > 0u) ? (1.0f / (float)c) : 0.0f;   // empty bin -> 0
    xa[si][k4+0] = v.x*m; xa[si][k4+1] = v.y*m;
    xa[si][k4+2] = v.z*m; xa[si][k4+3] = v.w*m;
  }
  __syncthreads();

  const int fg = tid & 31;
  const int pg = tid >> 5;
  const int f4c = fg << 2;
  const int prow = pg << 3;
  float ac[8][4];
  #pragma unroll
  for (int i = 0; i < 8; ++i) { ac[i][0]=ac[i][1]=ac[i][2]=ac[i][3]=0.f; }
  #pragma unroll 4
  for (int k = 0; k < H; ++k) {
    const float4 wv = *(const float4*)&wc[(size_t)k*H + f4c];
    #pragma unroll
    for (int i = 0; i < 8; ++i) {
      const float xv = xa[prow + i][k];
      ac[i][0] += xv*wv.x; ac[i][1] += xv*wv.y; ac[i][2] += xv*wv.z; ac[i][3] += xv*wv.w;
    }
  }
  __syncthreads();
  const float4 bv = *(const float4*)&bc[f4c];
  #pragma unroll
  for (int i = 0; i < 8; ++i) {
    float4 o;
    o.x = ac[i][0] + bv.x;
    o.y = ac[i][1] + bv.y;
    o.z = ac[i][2] + bv.z;
    o.w = ac[i][3] + bv.w;
    *(float4*)&xa[prow + i][f4c] = o;
  }
  __syncthreads();

  for (int j = tid; j < H * 16; j += 256) {
    const int ch = j >> 4;
    const int s4 = (j & 15) << 2;
    float4 o;
    o.x = xa[s4 + 0][ch];
    o.y = xa[s4 + 1][ch];
    o.z = xa[s4 + 2][ch];
    o.w = xa[s4 + 3][ch];
    *(float4*)&out[((size_t)plb*H + ch)*SS + s0 + s4] = o;
  }
}

extern "C" void kernel_launch(void* const* d_in, const int* in_sizes, int n_in,
                              void* d_out, int out_size, void* d_ws, size_t ws_size,
                              hipStream_t stream) {
  (void)in_sizes; (void)n_in; (void)out_size; (void)ws_size;
  const float* p      = (const float*)d_in[0];
  const float* wpos   = (const float*)d_in[1];
  const float* bpos   = (const float*)d_in[2];
  const float* blk0w  = (const float*)d_in[3];
  const float* blk0b  = (const float*)d_in[4];
  const float* blk1w  = (const float*)d_in[5];
  const float* blk1b  = (const float*)d_in[6];
  const float* blkscw = (const float*)d_in[7];
  const float* wc     = (const float*)d_in[8];
  const float* bc     = (const float*)d_in[9];
  float* out = (float*)d_out;

  char* ws = (char*)d_ws;
  _Float16* net  = (_Float16*)ws;                    // NP*H*2        = 40,960,000
  int* idx       = (int*)(ws + 40960000);            // 3*NP*4        =  1,920,000
  int* order     = (int*)(ws + 42880000);            // 3*NP*4        =  1,920,000
  int* cursor    = (int*)(ws + 44800000);            // 24*SS*4       =    393,216
  unsigned* cnt  = (unsigned*)(ws + 45193216);       // 24*SS*4       =    393,216
  _Float16* wb   = (_Float16*)(ws + 45586432);       // 5*81920*2     =    819,200
  float* sums    = (float*)(ws + 46405632);          // 24*SS*H*4     = 50,331,648
  float* pbufF   = (float*)(ws + 96737280);          // 24*625*H*4    =  7,680,000
  float* pbufL   = (float*)(ws + 104417280);         // 24*625*H*4    =  7,680,000
  unsigned* hist = (unsigned*)(ws + 112097280);      // 24*10*SS*4    =  3,932,160
                                                     // total         116,029,440 B
  _Float16* fea  = (_Float16*)d_out;                 // 25,165,824 B, dead before k_out2

  k_hist<<<24*NBLK, 256, 0, stream>>>(p, idx, hist);
  k_scan2<<<24, 256, 0, stream>>>(hist, cnt, cursor);
  k_reorder2<<<24*NBLK, 256, 0, stream>>>(idx, hist, order);
  k_wconv<<<200, 256, 0, stream>>>(blk0w, blk1w, blkscw, wb);

  k_block<0><<<2500, 512, 0, stream>>>(p, wpos, bpos, net, nullptr, idx,
                                       wb, blk0b, blk1b);

  for (int i = 1; i < 5; ++i) {
    k_poolA<0><<<79*24, 256, 0, stream>>>(net, order, fea, nullptr, pbufF, pbufL);
    k_poolB<0><<<78*24, 256, 0, stream>>>(order, cursor, fea, nullptr, pbufF, pbufL);
    k_block<1><<<GRID1, 512, 0, stream>>>(nullptr, nullptr, nullptr, net, fea, idx,
                                          wb + (size_t)i*81920,
                                          blk0b + (size_t)i*H,
                                          blk1b + (size_t)i*H);
  }

  k_poolA<1><<<79*24, 256, 0, stream>>>(net, order, nullptr, sums, pbufF, pbufL);
  k_poolB<1><<<78*24, 256, 0, stream>>>(order, cursor, nullptr, sums, pbufF, pbufL);
  k_out2<<<dim3(64, 24), 256, 0, stream>>>(sums, cnt, wc, bc, out);
}

// Round 16
// 470.328 us; speedup vs baseline: 1.0389x; 1.0343x over previous
//
#include <hip/hip_runtime.h>
#include <cstdint>
#include <cstddef>

#define NP     160000   // total points (B*T)
#define NB     8        // batch
#define TPB    20000    // points per batch
#define H      128      // hidden dim
#define SS     4096     // bins per plane (64*64)
#define NCHUNK 625      // TPB/32 (pool chunks)
#define NBLK   10       // sort chunks per (plane,batch)
#define PPB    2000     // points per sort chunk

typedef _Float16 half8  __attribute__((ext_vector_type(8)));
typedef _Float16 half4v __attribute__((ext_vector_type(4)));
typedef float    f32x16 __attribute__((ext_vector_type(16)));

__device__ __forceinline__ half8 reluh8(half8 x) {
  half8 z = (half8)(_Float16)0;
  return __builtin_elementwise_max(x, z);   // 4x v_pk_max_f16
}

// ---------------- per-chunk histograms + idx compute (fused) ----------------
__global__ __launch_bounds__(256) void k_hist(const float* __restrict__ p,
                                              int* __restrict__ idx,
                                              unsigned* __restrict__ hist) {
  __shared__ unsigned lh[SS];
  const int tid = threadIdx.x;
  const int plb = blockIdx.x % 24;
  const int blk = blockIdx.x / 24;
  const int pl = plb >> 3, b = plb & 7;
  for (int j = tid; j < SS; j += 256) lh[j] = 0;
  __syncthreads();
  const float DEN = (float)(1.0 + 0.1 + 1e-3);
  const float HI  = (float)(1.0 - 1e-3);
  const int nbase = b*TPB + blk*PPB;
  for (int j = tid; j < PPB; j += 256) {
    const int n = nbase + j;
    const float px = p[3*n], py = p[3*n+1], pz = p[3*n+2];
    float ca, cb;                       // plane column picks: (0,2) (0,1) (1,2)
    if (pl == 0)      { ca = px; cb = pz; }
    else if (pl == 1) { ca = px; cb = py; }
    else              { ca = py; cb = pz; }
    const float na = fminf(fmaxf(ca / DEN + 0.5f, 0.0f), HI);
    const float nb = fminf(fmaxf(cb / DEN + 0.5f, 0.0f), HI);
    const int bin = (int)(na * 64.0f) + 64 * (int)(nb * 64.0f);
    idx[pl*NP + n] = bin;
    atomicAdd(&lh[bin], 1u);
  }
  __syncthreads();
  unsigned* dst = hist + ((size_t)plb*NBLK + blk)*SS;
  for (int j = tid; j < SS; j += 256) dst[j] = lh[j];
}

// ---------------- scan: totals -> cnt, bin ENDS -> cursor, in-place block bases ----
__global__ __launch_bounds__(256) void k_scan2(unsigned* __restrict__ hist,
                                               unsigned* __restrict__ cnt,
                                               int* __restrict__ cursor) {
  __shared__ unsigned stot[SS];
  __shared__ unsigned ssum[256];
  __shared__ unsigned sbase[256];
  const int plb = blockIdx.x;
  const int tid = threadIdx.x;
  unsigned* hp = hist + (size_t)plb*NBLK*SS;
  for (int j = tid; j < SS; j += 256) {
    unsigned t = 0;
    #pragma unroll
    for (int blk = 0; blk < NBLK; ++blk) t += hp[blk*SS + j];
    stot[j] = t;
  }
  __syncthreads();
  unsigned local = 0;
  #pragma unroll
  for (int i = 0; i < 16; ++i) local += stot[tid*16 + i];
  ssum[tid] = local;
  __syncthreads();
  if (tid == 0) {
    unsigned run = 0;
    for (int i = 0; i < 256; ++i) { sbase[i] = run; run += ssum[i]; }
  }
  __syncthreads();
  unsigned run = sbase[tid];
  for (int i = 0; i < 16; ++i) {
    const int bin = tid*16 + i;
    const unsigned tot = stot[bin];
    cnt[plb*SS + bin] = tot;
    cursor[plb*SS + bin] = (int)(run + tot);       // END offset of bin
    unsigned acc = run;                            // in-place: counts -> bases
    #pragma unroll
    for (int blk = 0; blk < NBLK; ++blk) {
      const unsigned c = hp[blk*SS + bin];
      hp[blk*SS + bin] = acc;
      acc += c;
    }
    run += tot;
  }
}

// ---------------- reorder: local rank via LDS atomics, plain global stores ----
__global__ __launch_bounds__(256) void k_reorder2(const int* __restrict__ idx,
                                                  const unsigned* __restrict__ hist,
                                                  int* __restrict__ order) {
  __shared__ unsigned lrank[SS];
  const int tid = threadIdx.x;
  const int plb = blockIdx.x % 24;
  const int blk = blockIdx.x / 24;
  const int pl = plb >> 3, b = plb & 7;
  for (int j = tid; j < SS; j += 256) lrank[j] = 0;
  __syncthreads();
  const unsigned* bp = hist + ((size_t)plb*NBLK + blk)*SS;
  int* op = order + pl*NP + b*TPB;
  const int nbase = b*TPB + blk*PPB;
  for (int j = tid; j < PPB; j += 256) {
    const int n = nbase + j;
    const int bin = idx[pl*NP + n];
    const unsigned r = atomicAdd(&lrank[bin], 1u);
    op[bp[bin] + r] = (bin << 18) | n;
  }
}

// ---------------- weights fp32 -> f16 in MFMA B-fragment order ----------------
__global__ __launch_bounds__(256) void k_wconv(const float* __restrict__ w0,
                                               const float* __restrict__ w1,
                                               const float* __restrict__ wsc,
                                               _Float16* __restrict__ wb) {
  int t = blockIdx.x*256 + threadIdx.x;
  if (t >= 51200) return;
  int L = t / 10240, r = t % 10240;
  const float* src; _Float16* dst; int q;
  if (r < 4096)      { q = r;        src = w0  + L*32768; dst = wb + L*81920;         }
  else if (r < 8192) { q = r - 4096; src = wsc + L*32768; dst = wb + L*81920 + 32768; }
  else               { q = r - 8192; src = w1  + L*16384; dst = wb + L*81920 + 65536; }
  int kt = q >> 8, nt = (q >> 6) & 3, l = q & 63;
  int k0 = kt*16 + ((l >> 5) << 3);
  int n  = nt*32 + (l & 31);
  union { _Float16 h[8]; uint4 u; } o;
  #pragma unroll
  for (int j = 0; j < 8; ++j) o.h[j] = (_Float16)src[(size_t)(k0 + j)*H + n];
  *(uint4*)(dst + (size_t)q*8) = o.u;
}

// ---------------- Phase A: chunked segmented reduce, single-writer, NO atomics ----
template<int OP>
__global__ __launch_bounds__(256) void k_poolA(const _Float16* __restrict__ net,
                                               const int* __restrict__ order,
                                               _Float16* __restrict__ fea,
                                               float* __restrict__ sums,
                                               float* __restrict__ pbufF,
                                               float* __restrict__ pbufL) {
  const int tid   = threadIdx.x;
  const int plb   = blockIdx.x % 24;
  const int chunk = (blockIdx.x / 24) * 8 + (tid >> 5);
  if (chunk >= NCHUNK) return;
  const int gi = tid & 31, f4 = gi << 2;
  const int pl = plb >> 3, b = plb & 7;
  const int base = pl*NP + b*TPB + chunk*32;
  const int pkv = order[base + gi];
  const int prevbin = (chunk > 0)          ? (order[base - 1] >> 18) : -1;
  const int nextbin = (chunk < NCHUNK - 1) ? (order[base + 32] >> 18) : -1;

  uint2 v[32];
  #pragma unroll
  for (int i = 0; i < 32; ++i) {
    const int pk = __shfl(pkv, i, 32);
    v[i] = *(const uint2*)&net[(size_t)(pk & 0x3FFFF)*H + f4];
  }
  __builtin_amdgcn_sched_barrier(0);

  const size_t pslot = ((size_t)plb*NCHUNK + chunk)*H + f4;
  int cur = __shfl(pkv, 0, 32) >> 18;
  int segstart = 0;
  float a0, a1, a2, a3;
  if (OP == 0) { a0 = a1 = a2 = a3 = -3.0e38f; } else { a0 = a1 = a2 = a3 = 0.f; }

  #pragma unroll
  for (int i = 0; i < 32; ++i) {
    const int bin = __shfl(pkv, i, 32) >> 18;
    if (bin != cur) {
      const bool contin = (segstart == 0) && (prevbin == cur);
      if (!contin) {
        if (OP == 0) {
          union { _Float16 h[4]; uint2 u; } o;
          o.h[0]=(_Float16)a0; o.h[1]=(_Float16)a1; o.h[2]=(_Float16)a2; o.h[3]=(_Float16)a3;
          *(uint2*)&fea[((size_t)plb*SS + cur)*H + f4] = o.u;
        } else {
          *(float4*)&sums[((size_t)plb*SS + cur)*H + f4] = make_float4(a0,a1,a2,a3);
        }
      } else {
        *(float4*)&pbufF[pslot] = make_float4(a0,a1,a2,a3);
      }
      cur = bin; segstart = i;
      if (OP == 0) { a0 = a1 = a2 = a3 = -3.0e38f; } else { a0 = a1 = a2 = a3 = 0.f; }
    }
    union { uint2 u; _Float16 h[4]; } w;
    w.u = v[i];
    if (OP == 0) {
      a0 = fmaxf(a0, (float)w.h[0]); a1 = fmaxf(a1, (float)w.h[1]);
      a2 = fmaxf(a2, (float)w.h[2]); a3 = fmaxf(a3, (float)w.h[3]);
    } else {
      a0 += (float)w.h[0]; a1 += (float)w.h[1];
      a2 += (float)w.h[2]; a3 += (float)w.h[3];
    }
  }
  const bool contin = (segstart == 0) && (prevbin == cur);
  const bool extend = (nextbin == cur);
  if (!contin && !extend) {
    if (OP == 0) {
      union { _Float16 h[4]; uint2 u; } o;
      o.h[0]=(_Float16)a0; o.h[1]=(_Float16)a1; o.h[2]=(_Float16)a2; o.h[3]=(_Float16)a3;
      *(uint2*)&fea[((size_t)plb*SS + cur)*H + f4] = o.u;
    } else {
      *(float4*)&sums[((size_t)plb*SS + cur)*H + f4] = make_float4(a0,a1,a2,a3);
    }
  } else if (contin) {
    *(float4*)&pbufF[pslot] = make_float4(a0,a1,a2,a3);
  } else {
    *(float4*)&pbufL[pslot] = make_float4(a0,a1,a2,a3);
  }
}

// ---------------- Phase B: combine cross-boundary bins (first boundary owns) ----
template<int OP>
__global__ __launch_bounds__(256) void k_poolB(const int* __restrict__ order,
                                               const int* __restrict__ cursor,
                                               _Float16* __restrict__ fea,
                                               float* __restrict__ sums,
                                               const float* __restrict__ pbufF,
                                               const float* __restrict__ pbufL) {
  const int tid = threadIdx.x;
  const int plb = blockIdx.x % 24;
  const int bnd = (blockIdx.x / 24) * 8 + (tid >> 5);
  if (bnd >= NCHUNK - 1) return;
  const int gi = tid & 31, f4 = gi << 2;
  const int pl = plb >> 3, b = plb & 7;
  const int base = pl*NP + b*TPB;
  const int pos  = (bnd + 1) * 32;
  const int binR = order[base + pos] >> 18;
  const int binL = order[base + pos - 1] >> 18;
  if (binL != binR) return;
  const int beta = binR;
  const int e = cursor[plb*SS + beta];
  const int s = (beta > 0) ? cursor[plb*SS + beta - 1] : 0;
  const int cs = s >> 5, ce = (e - 1) >> 5;
  if (cs != bnd) return;
  float4 acc = *(const float4*)&pbufL[((size_t)plb*NCHUNK + cs)*H + f4];
  #pragma unroll 4
  for (int c = cs + 1; c <= ce; ++c) {
    const float4 q = *(const float4*)&pbufF[((size_t)plb*NCHUNK + c)*H + f4];
    if (OP == 0) {
      acc.x = fmaxf(acc.x, q.x); acc.y = fmaxf(acc.y, q.y);
      acc.z = fmaxf(acc.z, q.z); acc.w = fmaxf(acc.w, q.w);
    } else {
      acc.x += q.x; acc.y += q.y; acc.z += q.z; acc.w += q.w;
    }
  }
  if (OP == 0) {
    union { _Float16 h[4]; uint2 u; } o;
    o.h[0]=(_Float16)acc.x; o.h[1]=(_Float16)acc.y;
    o.h[2]=(_Float16)acc.z; o.h[3]=(_Float16)acc.w;
    *(uint2*)&fea[((size_t)plb*SS + beta)*H + f4] = o.u;
  } else {
    *(float4*)&sums[((size_t)plb*SS + beta)*H + f4] = acc;
  }
}

// ---------------- fused ResnetBlockFC via mfma_f32_32x32x16_f16 ----------------
// R12 configuration — session best (471.0 us), locked in after R13-R15
// falsified fusion / XCD-remap / setprio / persistent-prefetch variants.
// 512 thr / 8 waves; wave w owns a 32x32 output tile (c=w&3, r=w>>2).
// Deferred shortcut: out = x@Wsc + h@W1 (concat K=384) so only ONE f32x16
// accumulator is live at a time (16 regs vs 64 — the R7/R8/R11 spill wall).
// Phase A: fc0 (aR, 16 regs) -> h to Hs. Phase B1: x@Wsc (aS) BEFORE the
// barrier (hides it). Phase B2: h@W1 into aS.
// LDS: Xs 32KB (pitch 512B, swz (row&31)<<4) + Hs 16KB separate (pitch 256B,
// swz (row&15)<<4) = 48KB. Unroll 4/2 = proven spill-free schedule.
template<int MODE>
__global__ __launch_bounds__(512, 6) void k_block(
    const float* __restrict__ p,
    const float* __restrict__ wpos, const float* __restrict__ bpos,
    _Float16* __restrict__ net,
    const _Float16* __restrict__ fea, const int* __restrict__ idx,
    const _Float16* __restrict__ wb,
    const float* __restrict__ b0, const float* __restrict__ b1)
{
  __shared__ char smem[49152];
  char* Xs = smem;            // x[64][256] f16
  char* Hs = smem + 32768;    // h[64][128] f16 (separate — no aliasing)
  const int tid = threadIdx.x;
  const int n0  = blockIdx.x * 64;

  if (MODE == 0) {
    for (int j = tid; j < 64*64; j += 512) {
      int pt = j >> 6, k4 = (j & 63) << 2;
      int n = n0 + pt;
      float px = p[3*n], py = p[3*n+1], pz = p[3*n+2];
      float4 a  = *(const float4*)&bpos[k4];
      float4 wx = *(const float4*)&wpos[k4];
      float4 wy = *(const float4*)&wpos[256 + k4];
      float4 wz = *(const float4*)&wpos[512 + k4];
      a.x += px*wx.x + py*wy.x + pz*wz.x;
      a.y += px*wx.y + py*wy.y + pz*wz.y;
      a.z += px*wx.z + py*wy.z + pz*wz.z;
      a.w += px*wx.w + py*wy.w + pz*wz.w;
      union { _Float16 h[4]; uint2 u; } o;
      o.h[0] = (_Float16)a.x; o.h[1] = (_Float16)a.y;
      o.h[2] = (_Float16)a.z; o.h[3] = (_Float16)a.w;
      *(uint2*)(Xs + ((pt*512 + k4*2) ^ ((pt & 31) << 4))) = o.u;
    }
  } else {
    // merged staging: net-row copy + 3-plane gather; sums in packed f16
    for (int j = tid; j < 64*32; j += 512) {
      int pt = j >> 5, k4 = (j & 31) << 2;
      int n = n0 + pt;
      int b = n / TPB;
      uint2 vleft = *(const uint2*)&net[(size_t)n*H + k4];
      union { uint2 u; half4v h; } w0g, w1g, w2g, o;
      w0g.u = *(const uint2*)&fea[(((size_t)(0*NB + b))*SS + idx[0*NP + n])*H + k4];
      w1g.u = *(const uint2*)&fea[(((size_t)(1*NB + b))*SS + idx[1*NP + n])*H + k4];
      w2g.u = *(const uint2*)&fea[(((size_t)(2*NB + b))*SS + idx[2*NP + n])*H + k4];
      o.h = (w0g.h + w1g.h) + w2g.h;           // v_pk_add_f16
      const int sw = (pt & 31) << 4;
      *(uint2*)(Xs + ((pt*512 + k4*2) ^ sw)) = vleft;
      *(uint2*)(Xs + ((pt*512 + 256 + k4*2) ^ sw)) = o.u;
    }
  }
  __syncthreads();

  const int w  = tid >> 6;          // wave 0..7
  const int c  = w & 3;             // col tile
  const int r  = w >> 2;            // row half
  const int ln = tid & 63;
  const int l5 = ln >> 5;
  const int lr = ln & 31;
  const int swx   = lr << 4;        // Xs swizzle: (row&31)<<4; (r*32)&31 == 0
  const int xbase = lr*512 + l5*16 + r*16384;
  const int col   = c*32 + lr;
  const _Float16* wb0 = wb;
  const _Float16* wbs = wb + 32768;
  const _Float16* wb1 = wb + 65536;

  // ---- phase A: fc0 on relu(x), K=256 (16 acc regs) ----
  f32x16 aR = {};
  #pragma unroll 4
  for (int kt = 0; kt < 16; ++kt) {
    half8 x  = *(const half8*)(Xs + ((xbase + kt*32) ^ swx));
    half8 rx = reluh8(x);
    half8 bw = *(const half8*)(wb0 + ((kt*4 + c)*64 + ln)*8);
    aR = __builtin_amdgcn_mfma_f32_32x32x16_f16(rx, bw, aR, 0, 0, 0);
  }
  // h = relu(aR + b0) -> Hs  (C/D: col = lane&31, row = (reg&3)+8*(reg>>2)+4*(lane>>5))
  const float bb0 = b0[col];
  #pragma unroll
  for (int reg = 0; reg < 16; ++reg) {
    const int ro  = (reg & 3) + 8*(reg >> 2) + 4*l5;
    const int row = r*32 + ro;
    const float v = fmaxf(aR[reg] + bb0, 0.f);
    *(_Float16*)(Hs + ((row*256 + col*2) ^ ((row & 15) << 4))) = (_Float16)v;
  }

  // ---- phase B1: shortcut x@Wsc (reads Xs only — overlaps the barrier) ----
  f32x16 aS = {};
  #pragma unroll 4
  for (int kt = 0; kt < 16; ++kt) {
    half8 x  = *(const half8*)(Xs + ((xbase + kt*32) ^ swx));
    half8 bs = *(const half8*)(wbs + ((kt*4 + c)*64 + ln)*8);
    aS = __builtin_amdgcn_mfma_f32_32x32x16_f16(x, bs, aS, 0, 0, 0);
  }
  __syncthreads();   // Hs writes from all waves visible

  // ---- phase B2: dx = h@W1, accumulate into aS ----
  const int hbase = (r*32 + lr)*256 + l5*16;
  const int swh   = (lr & 15) << 4;
  #pragma unroll 2
  for (int kt = 0; kt < 8; ++kt) {
    half8 h  = *(const half8*)(Hs + ((hbase + kt*32) ^ swh));
    half8 bf = *(const half8*)(wb1 + ((kt*4 + c)*64 + ln)*8);
    aS = __builtin_amdgcn_mfma_f32_32x32x16_f16(h, bf, aS, 0, 0, 0);
  }

  const float bb1 = b1[col];
  #pragma unroll
  for (int reg = 0; reg < 16; ++reg) {
    const int ro = (reg & 3) + 8*(reg >> 2) + 4*l5;
    net[(size_t)(n0 + r*32 + ro)*H + col] = (_Float16)(aS[reg] + bb1);
  }
}

// ---------------- mean-normalize + fc_c GEMM + transpose-out ----------------
__global__ __launch_bounds__(256) void k_out2(const float* __restrict__ sums,
                                              const unsigned* __restrict__ cnt,
                                              const float* __restrict__ wc,
                                              const float* __restrict__ bc,
                                              float* __restrict__ out) {
  __shared__ float xa[64][132];
  const int plb = blockIdx.y;
  const int s0  = blockIdx.x << 6;
  const int tid = threadIdx.x;

  for (int j = tid; j < 64*32; j += 256) {
    int si = j >> 5, k4 = (j & 31) << 2;
    int s = s0 + si;
    float4 v = *(const float4*)&sums[((size_t)plb*SS + s)*H + k4];
    unsigned c = cnt[(size_t)plb*SS + s];
    float m = (c > 0u) ? (1.0f / (float)c) : 0.0f;   // empty bin -> 0
    xa[si][k4+0] = v.x*m; xa[si][k4+1] = v.y*m;
    xa[si][k4+2] = v.z*m; xa[si][k4+3] = v.w*m;
  }
  __syncthreads();

  const int fg = tid & 31;
  const int pg = tid >> 5;
  const int f4c = fg << 2;
  const int prow = pg << 3;
  float ac[8][4];
  #pragma unroll
  for (int i = 0; i < 8; ++i) { ac[i][0]=ac[i][1]=ac[i][2]=ac[i][3]=0.f; }
  #pragma unroll 4
  for (int k = 0; k < H; ++k) {
    const float4 wv = *(const float4*)&wc[(size_t)k*H + f4c];
    #pragma unroll
    for (int i = 0; i < 8; ++i) {
      const float xv = xa[prow + i][k];
      ac[i][0] += xv*wv.x; ac[i][1] += xv*wv.y; ac[i][2] += xv*wv.z; ac[i][3] += xv*wv.w;
    }
  }
  __syncthreads();
  const float4 bv = *(const float4*)&bc[f4c];
  #pragma unroll
  for (int i = 0; i < 8; ++i) {
    float4 o;
    o.x = ac[i][0] + bv.x;
    o.y = ac[i][1] + bv.y;
    o.z = ac[i][2] + bv.z;
    o.w = ac[i][3] + bv.w;
    *(float4*)&xa[prow + i][f4c] = o;
  }
  __syncthreads();

  for (int j = tid; j < H * 16; j += 256) {
    const int ch = j >> 4;
    const int s4 = (j & 15) << 2;
    float4 o;
    o.x = xa[s4 + 0][ch];
    o.y = xa[s4 + 1][ch];
    o.z = xa[s4 + 2][ch];
    o.w = xa[s4 + 3][ch];
    *(float4*)&out[((size_t)plb*H + ch)*SS + s0 + s4] = o;
  }
}

extern "C" void kernel_launch(void* const* d_in, const int* in_sizes, int n_in,
                              void* d_out, int out_size, void* d_ws, size_t ws_size,
                              hipStream_t stream) {
  (void)in_sizes; (void)n_in; (void)out_size; (void)ws_size;
  const float* p      = (const float*)d_in[0];
  const float* wpos   = (const float*)d_in[1];
  const float* bpos   = (const float*)d_in[2];
  const float* blk0w  = (const float*)d_in[3];
  const float* blk0b  = (const float*)d_in[4];
  const float* blk1w  = (const float*)d_in[5];
  const float* blk1b  = (const float*)d_in[6];
  const float* blkscw = (const float*)d_in[7];
  const float* wc     = (const float*)d_in[8];
  const float* bc     = (const float*)d_in[9];
  float* out = (float*)d_out;

  char* ws = (char*)d_ws;
  _Float16* net  = (_Float16*)ws;                    // NP*H*2        = 40,960,000
  int* idx       = (int*)(ws + 40960000);            // 3*NP*4        =  1,920,000
  int* order     = (int*)(ws + 42880000);            // 3*NP*4        =  1,920,000
  int* cursor    = (int*)(ws + 44800000);            // 24*SS*4       =    393,216
  unsigned* cnt  = (unsigned*)(ws + 45193216);       // 24*SS*4       =    393,216
  _Float16* wb   = (_Float16*)(ws + 45586432);       // 5*81920*2     =    819,200
  float* sums    = (float*)(ws + 46405632);          // 24*SS*H*4     = 50,331,648
  float* pbufF   = (float*)(ws + 96737280);          // 24*625*H*4    =  7,680,000
  float* pbufL   = (float*)(ws + 104417280);         // 24*625*H*4    =  7,680,000
  unsigned* hist = (unsigned*)(ws + 112097280);      // 24*10*SS*4    =  3,932,160
                                                     // total         116,029,440 B
  _Float16* fea  = (_Float16*)d_out;                 // 25,165,824 B, dead before k_out2

  k_hist<<<24*NBLK, 256, 0, stream>>>(p, idx, hist);
  k_scan2<<<24, 256, 0, stream>>>(hist, cnt, cursor);
  k_reorder2<<<24*NBLK, 256, 0, stream>>>(idx, hist, order);
  k_wconv<<<200, 256, 0, stream>>>(blk0w, blk1w, blkscw, wb);

  k_block<0><<<2500, 512, 0, stream>>>(p, wpos, bpos, net, nullptr, idx,
                                       wb, blk0b, blk1b);

  for (int i = 1; i < 5; ++i) {
    k_poolA<0><<<79*24, 256, 0, stream>>>(net, order, fea, nullptr, pbufF, pbufL);
    k_poolB<0><<<78*24, 256, 0, stream>>>(order, cursor, fea, nullptr, pbufF, pbufL);
    k_block<1><<<2500, 512, 0, stream>>>(nullptr, nullptr, nullptr, net, fea, idx,
                                         wb + (size_t)i*81920,
                                         blk0b + (size_t)i*H,
                                         blk1b + (size_t)i*H);
  }

  k_poolA<1><<<79*24, 256, 0, stream>>>(net, order, nullptr, sums, pbufF, pbufL);
  k_poolB<1><<<78*24, 256, 0, stream>>>(order, cursor, nullptr, sums, pbufF, pbufL);
  k_out2<<<dim3(64, 24), 256, 0, stream>>>(sums, cnt, wc, bc, out);
}